// Round 2
// baseline (1517.312 us; speedup 1.0000x reference)
//
#include <hip/hip_runtime.h>
#include <math.h>

#define TS 10
#define TD 128
#define TE 64
#define BT 8
#define NTHR 320
#define HSTR 132          // floats per Hs row: 128+4 pad -> row step == 4 banks (mod 32)
#define QSTR 68           // floats per Q/K/Vd/G/t row: 64+4 pad
#define NHROWS (TS*BT)    // 80

#define HS_FLOATS (NHROWS*HSTR)    // 10560
#define BUF_FLOATS (40*QSTR)       // 2720
#define P_FLOATS (BT*TS*12)        // 960
#define LDS_FLOATS (HS_FLOATS + 3*BUF_FLOATS + P_FLOATS)   // 19680 -> 78720 B (2 WG/CU)

#define INVSQRT10 0.31622776601683794f

// ---------------- POS precompute (fp64, once per launch, into d_ws) ----------
__global__ void pos_kernel(float* __restrict__ pos) {
    for (int idx = threadIdx.x; idx < TS * TD; idx += blockDim.x) {
        int n = idx / TD, d = idx % TD;
        int j = d >> 1;
        double ang = (double)n / pow(1000.0, 2.0 * (double)j / (double)TD);
        double v = (d & 1) ? cos(ang) : sin(ang);
        pos[idx] = (float)v;
    }
}

// ---------------- generic M-row x C-col fp32 GEMM tile ----------------------
// OUT[m][c] (MxC) = sum_k A[a0 + m*astr + k] * W[k*ws + c], k in [0,K)
// A, O are LDS float*; W is global float* pre-offset to col0. C multiple of 4.
template <int M, int C, int K, bool ADD>
__device__ __forceinline__ void gemm_f32(
    const float* __restrict__ Ap, int a0, int astr,
    const float* __restrict__ W, int ws,
    float* __restrict__ Op, int o0, int ostr,
    float scale)
{
    float acc[M][C];
#pragma unroll
    for (int m = 0; m < M; m++)
#pragma unroll
        for (int c = 0; c < C; c++) acc[m][c] = 0.f;

    for (int k = 0; k < K; k += 4) {
        float4 va[M];
#pragma unroll
        for (int m = 0; m < M; m++)
            va[m] = *(const float4*)(Ap + a0 + m * astr + k);
        float wv[4][C];
#pragma unroll
        for (int kk = 0; kk < 4; kk++)
#pragma unroll
            for (int cg = 0; cg < C / 4; cg++) {
                float4 w4 = *(const float4*)(W + (size_t)(k + kk) * ws + cg * 4);
                wv[kk][cg * 4 + 0] = w4.x; wv[kk][cg * 4 + 1] = w4.y;
                wv[kk][cg * 4 + 2] = w4.z; wv[kk][cg * 4 + 3] = w4.w;
            }
#pragma unroll
        for (int m = 0; m < M; m++) {
            float am[4];
            am[0] = va[m].x; am[1] = va[m].y; am[2] = va[m].z; am[3] = va[m].w;
#pragma unroll
            for (int kk = 0; kk < 4; kk++)
#pragma unroll
                for (int c = 0; c < C; c++)
                    acc[m][c] = fmaf(am[kk], wv[kk][c], acc[m][c]);
        }
    }
#pragma unroll
    for (int m = 0; m < M; m++) {
        float* op = Op + o0 + m * ostr;
#pragma unroll
        for (int cg = 0; cg < C / 4; cg++) {
            float4 r;
            if constexpr (ADD) {
                float4 v = *(float4*)(op + cg * 4);
                r.x = fmaf(scale, acc[m][cg * 4 + 0], v.x);
                r.y = fmaf(scale, acc[m][cg * 4 + 1], v.y);
                r.z = fmaf(scale, acc[m][cg * 4 + 2], v.z);
                r.w = fmaf(scale, acc[m][cg * 4 + 3], v.w);
            } else {
                r.x = scale * acc[m][cg * 4 + 0];
                r.y = scale * acc[m][cg * 4 + 1];
                r.z = scale * acc[m][cg * 4 + 2];
                r.w = scale * acc[m][cg * 4 + 3];
            }
            *(float4*)(op + cg * 4) = r;
        }
    }
}

// ---------------- fused kernel ----------------------------------------------
extern "C" __global__ __launch_bounds__(NTHR, 2)
void trans_fused(const float* __restrict__ x,
                 const float* __restrict__ L_w, const float* __restrict__ UL_w,
                 const float* __restrict__ WQ,  const float* __restrict__ WK,
                 const float* __restrict__ WVd, const float* __restrict__ WVu,
                 const float* __restrict__ WQ2, const float* __restrict__ WK2,
                 const float* __restrict__ WVd2,const float* __restrict__ WVu2,
                 const float* __restrict__ qin1,const float* __restrict__ qout1,
                 const float* __restrict__ qin2,const float* __restrict__ qout2,
                 const float* __restrict__ POSb, float* __restrict__ out)
{
    extern __shared__ float lds[];
    float* Hs = lds;                      // [80][HSTR], row = b*10 + n
    float* Qb = lds + HS_FLOATS;          // [40][QSTR], row r' = b4*10 + n ; also G / t(lo)
    float* Kb = Qb + BUF_FLOATS;          // [40][QSTR]                     ; also t(hi)
    float* Vb = Kb + BUF_FLOATS;          // [40][QSTR]
    float* Pb = Vb + BUF_FLOATS;          // [8][10][12] logits -> softmax weights
    float* Tb = Qb;                       // t buffer: 80 rows spanning Qb+Kb

    const int tid = threadIdx.x;
    const int gb0 = blockIdx.x * BT;

    // ---- Phase 0: h = x @ L_w + POS (fp64 accum; 10240/320 = 32 per thread) ----
    for (int idx = tid; idx < NHROWS * TD; idx += NTHR) {
        int r = idx >> 7, d = idx & 127;
        int b = r / 10, n = r - b * 10;
        const float* xp = x + ((size_t)(gb0 + b) * TS + n) * 4;
        double acc = (double)POSb[n * TD + d];
#pragma unroll
        for (int c = 0; c < 4; c++)
            acc += (double)xp[c] * (double)L_w[c * TD + d];
        Hs[r * HSTR + d] = (float)acc;
    }
    __syncthreads();

    for (int layer = 0; layer < 2; ++layer) {
        const float* pWQ  = layer ? WQ2  : WQ;
        const float* pWK  = layer ? WK2  : WK;
        const float* pWVd = layer ? WVd2 : WVd;
        const float* pWVu = layer ? WVu2 : WVu;
        const float* pqin = layer ? qin2 : qin1;
        const float* pqou = layer ? qout2 : qout1;

        for (int hb = 0; hb < 2; ++hb) {
            // ---- QKV (fp32): 240 tiles = mat(3) x n(10) x cg(8); m along b4 ----
            if (tid < 240) {
                int p = tid / 80, t2 = tid % 80;
                int n = t2 >> 3, cg = t2 & 7;
                const float* Wp = (p == 0 ? pWQ : (p == 1 ? pWK : pWVd)) + cg * 8;
                float* Ob = (p == 0 ? Qb : (p == 1 ? Kb : Vb));
                gemm_f32<4, 8, TD, false>(Hs, (hb * 40 + n) * HSTR, 10 * HSTR,
                                          Wp, TE,
                                          Ob, n * QSTR + cg * 8, 10 * QSTR, 1.f);
            }
            __syncthreads();

            // ---- logits (fp64 dot): 220 = b4(4) x 55 (i,j<=i) ----
            if (tid < 220) {
                int b4 = tid / 55, pr = tid % 55;
                int i = 0, base = 0;
                while (pr >= base + i + 1) { base += i + 1; i++; }
                int j = pr - base;
                const float* qr = Qb + (b4 * 10 + i) * QSTR;
                const float* kr = Kb + (b4 * 10 + j) * QSTR;
                double acc = 0.0;
                for (int e = 0; e < TE; e += 4) {
                    float4 q4 = *(const float4*)(qr + e);
                    float4 k4 = *(const float4*)(kr + e);
                    acc = fma((double)q4.x, (double)k4.x, acc);
                    acc = fma((double)q4.y, (double)k4.y, acc);
                    acc = fma((double)q4.z, (double)k4.z, acc);
                    acc = fma((double)q4.w, (double)k4.w, acc);
                }
                Pb[(hb * 4 + b4) * 120 + i * 12 + j] = (float)acc;
            }
            __syncthreads();

            // ---- softmax over keys j<=i (fp32, matches reference) ----
            if (tid < 40) {
                int b4 = tid / 10, i = tid % 10;
                float* pr = Pb + (hb * 4 + b4) * 120 + i * 12;
                float m = pr[0];
#pragma unroll
                for (int j = 1; j < TS; j++) if (j <= i) m = fmaxf(m, pr[j]);
                float sum = 0.f;
#pragma unroll
                for (int j = 0; j < TS; j++) if (j <= i) { float e = expf(pr[j] - m); pr[j] = e; sum += e; }
#pragma unroll
                for (int j = 0; j < TS; j++) pr[j] = (j <= i) ? pr[j] / sum : 0.f;
            }
            __syncthreads();

            // ---- G[r'=b4*10+q][e] = sum_k P * Vd[b4*10+k][e]; into Qb (Q dead) ----
            // 640 float4-tasks / 320 = 2 per thread
            for (int oi = tid; oi < 40 * 16; oi += NTHR) {
                int rr = oi >> 4, e4 = (oi & 15) * 4;
                int b4 = rr / 10, q = rr - b4 * 10;
                const float* pp = Pb + (hb * 4 + b4) * 120 + q * 12;
                float4 g = {0.f, 0.f, 0.f, 0.f};
#pragma unroll
                for (int k = 0; k < TS; k++) {
                    float p = pp[k];
                    float4 v = *(const float4*)(Vb + (b4 * 10 + k) * QSTR + e4);
                    g.x = fmaf(p, v.x, g.x);
                    g.y = fmaf(p, v.y, g.y);
                    g.z = fmaf(p, v.z, g.z);
                    g.w = fmaf(p, v.w, g.w);
                }
                *(float4*)(Qb + rr * QSTR + e4) = g;
            }
            __syncthreads();

            // ---- DE: Hs(half) += invsqrt10 * G @ WVu ; 320 tiles = q(10) x cg(32) ----
            {
                int q = tid >> 5, cg = tid & 31;
                gemm_f32<4, 4, TE, true>(Qb, q * QSTR, 10 * QSTR,
                                         pWVu + cg * 4, TD,
                                         Hs, (hb * 40 + q) * HSTR + cg * 4, 10 * HSTR,
                                         INVSQRT10);
            }
            __syncthreads();
        } // hb

        // ---- ques-in: t[80][64] = Hs @ quesin[n] ; 320 tiles = bg(2) x n(10) x cg(16) ----
        {
            int bg = tid / 160, t2 = tid % 160;
            int n = t2 >> 4, cg = t2 & 15;
            gemm_f32<4, 4, TD, false>(Hs, (bg * 40 + n) * HSTR, 10 * HSTR,
                                      pqin + (size_t)n * TD * TE + cg * 4, TE,
                                      Tb, (bg * 40 + n) * QSTR + cg * 4, 10 * QSTR, 1.f);
        }
        __syncthreads();

        // ---- ques-out: Hs = t @ quesout[n] ; 320 tiles = bg(2) x n(10) x cg(16) ----
        {
            int bg = tid / 160, t2 = tid % 160;
            int n = t2 >> 4, cg = t2 & 15;
            gemm_f32<4, 8, TE, false>(Tb, (bg * 40 + n) * QSTR, 10 * QSTR,
                                      pqou + (size_t)n * TE * TD + cg * 8, TD,
                                      Hs, (bg * 40 + n) * HSTR + cg * 8, 10 * HSTR, 1.f);
        }
        __syncthreads();
    } // layer

    // ---- out = Hs @ UL_w : 320 outs, exactly 1 per thread ----
    {
        int r = tid >> 2, c = tid & 3;
        int b = r / 10, n = r - b * 10;
        const float* hr = Hs + r * HSTR;
        float acc = 0.f;
        for (int d = 0; d < TD; d += 4) {
            float4 h4 = *(const float4*)(hr + d);
            acc = fmaf(h4.x, UL_w[(d + 0) * 4 + c], acc);
            acc = fmaf(h4.y, UL_w[(d + 1) * 4 + c], acc);
            acc = fmaf(h4.z, UL_w[(d + 2) * 4 + c], acc);
            acc = fmaf(h4.w, UL_w[(d + 3) * 4 + c], acc);
        }
        out[((size_t)(gb0 + b) * TS + n) * 4 + c] = acc;
    }
}

// ---------------- host launch -----------------------------------------------
extern "C" void kernel_launch(void* const* d_in, const int* in_sizes, int n_in,
                              void* d_out, int out_size, void* d_ws, size_t ws_size,
                              hipStream_t stream) {
    const float* x    = (const float*)d_in[0];
    const float* L_w  = (const float*)d_in[1];
    const float* UL_w = (const float*)d_in[2];
    const float* WQ   = (const float*)d_in[3];
    const float* WK   = (const float*)d_in[4];
    const float* WVd  = (const float*)d_in[5];
    const float* WVu  = (const float*)d_in[6];
    const float* WQ2  = (const float*)d_in[7];
    const float* WK2  = (const float*)d_in[8];
    const float* WVd2 = (const float*)d_in[9];
    const float* WVu2 = (const float*)d_in[10];
    const float* qin1 = (const float*)d_in[11];
    const float* qout1= (const float*)d_in[12];
    const float* qin2 = (const float*)d_in[13];
    const float* qout2= (const float*)d_in[14];
    float* out = (float*)d_out;
    float* POSb = (float*)d_ws;

    int B = in_sizes[0] / (TS * 4);
    size_t lds_bytes = (size_t)LDS_FLOATS * sizeof(float);

    (void)hipFuncSetAttribute((const void*)trans_fused,
                              hipFuncAttributeMaxDynamicSharedMemorySize,
                              (int)lds_bytes);

    pos_kernel<<<dim3(1), dim3(256), 0, stream>>>(POSb);
    trans_fused<<<dim3(B / BT), dim3(NTHR), lds_bytes, stream>>>(
        x, L_w, UL_w, WQ, WK, WVd, WVu, WQ2, WK2, WVd2, WVu2,
        qin1, qout1, qin2, qout2, POSb, out);
}

// Round 3
// 1279.325 us; speedup vs baseline: 1.1860x; 1.1860x over previous
//
#include <hip/hip_runtime.h>
#include <math.h>

#define TS 10
#define TD 128
#define TE 64
#define BT 8
#define NTHR 256
#define HSTR 132          // floats per Hs row: 128+4 pad (row step = 4 banks mod 32)
#define QSTR 68           // floats per Q/K/Vd/G/t row: 64+4 pad
#define NHROWS (TS*BT)    // 80

#define HS_FLOATS (NHROWS*HSTR)    // 10560
#define BUF_FLOATS (40*QSTR)       // 2720
#define P_FLOATS (BT*TS*12)        // 960
#define LDS_FLOATS (HS_FLOATS + 3*BUF_FLOATS + P_FLOATS)   // 19680 -> 78720 B (2 WG/CU @256thr)

#define INVSQRT10 0.31622776601683794f

// ---------------- POS precompute (fp64, once per launch, into d_ws) ----------
__global__ void pos_kernel(float* __restrict__ pos) {
    for (int idx = threadIdx.x; idx < TS * TD; idx += blockDim.x) {
        int n = idx / TD, d = idx % TD;
        int j = d >> 1;
        double ang = (double)n / pow(1000.0, 2.0 * (double)j / (double)TD);
        double v = (d & 1) ? cos(ang) : sin(ang);
        pos[idx] = (float)v;
    }
}

// ---------------- M-row x C-col fp32 GEMM tile, register double-buffered -----
// OUT[m][c] = sum_k A[a0+m*astr+k] * W[k*ws+c].  A,O in LDS; W in global.
// K multiple of 8. Loads for step k+4 issue BEFORE the FMA block of step k,
// so L2-latency of the W stream hides under ~256 cycles of FMA issue.
template <int M, int C, int K, bool ADD>
__device__ __forceinline__ void gemm_f32(
    const float* __restrict__ Ap, int a0, int astr,
    const float* __restrict__ W, int ws,
    float* __restrict__ Op, int o0, int ostr,
    float scale)
{
    constexpr int CG = C / 4;
    float acc[M][C];
#pragma unroll
    for (int m = 0; m < M; m++)
#pragma unroll
        for (int c = 0; c < C; c++) acc[m][c] = 0.f;

    float4 aR0[M], aR1[M], wR0[4 * CG], wR1[4 * CG];

    auto loadA = [&](float4* aR, int k) {
#pragma unroll
        for (int m = 0; m < M; m++)
            aR[m] = *(const float4*)(Ap + a0 + m * astr + k);
    };
    auto loadW = [&](float4* wR, int k) {
#pragma unroll
        for (int kk = 0; kk < 4; kk++)
#pragma unroll
            for (int cg = 0; cg < CG; cg++)
                wR[kk * CG + cg] = *(const float4*)(W + (size_t)(k + kk) * ws + cg * 4);
    };
    auto compute = [&](const float4* aR, const float4* wR) {
#pragma unroll
        for (int m = 0; m < M; m++) {
            const float* af = (const float*)&aR[m];
#pragma unroll
            for (int kk = 0; kk < 4; kk++) {
                float a = af[kk];
#pragma unroll
                for (int cg = 0; cg < CG; cg++) {
                    const float* wf = (const float*)&wR[kk * CG + cg];
#pragma unroll
                    for (int j = 0; j < 4; j++)
                        acc[m][cg * 4 + j] = fmaf(a, wf[j], acc[m][cg * 4 + j]);
                }
            }
        }
    };

    loadA(aR0, 0); loadW(wR0, 0);
    int k = 0;
#pragma unroll 1
    for (; k + 8 < K; k += 8) {
        loadA(aR1, k + 4); loadW(wR1, k + 4);   // prefetch k+4
        compute(aR0, wR0);                      // compute k
        loadA(aR0, k + 8); loadW(wR0, k + 8);   // prefetch k+8
        compute(aR1, wR1);                      // compute k+4
    }
    // k == K-8 here
    loadA(aR1, K - 4); loadW(wR1, K - 4);
    compute(aR0, wR0);
    compute(aR1, wR1);

#pragma unroll
    for (int m = 0; m < M; m++) {
        float* op = Op + o0 + m * ostr;
#pragma unroll
        for (int cg = 0; cg < CG; cg++) {
            float4 r;
            if constexpr (ADD) {
                float4 v = *(float4*)(op + cg * 4);
                r.x = fmaf(scale, acc[m][cg * 4 + 0], v.x);
                r.y = fmaf(scale, acc[m][cg * 4 + 1], v.y);
                r.z = fmaf(scale, acc[m][cg * 4 + 2], v.z);
                r.w = fmaf(scale, acc[m][cg * 4 + 3], v.w);
            } else {
                r.x = scale * acc[m][cg * 4 + 0];
                r.y = scale * acc[m][cg * 4 + 1];
                r.z = scale * acc[m][cg * 4 + 2];
                r.w = scale * acc[m][cg * 4 + 3];
            }
            *(float4*)(op + cg * 4) = r;
        }
    }
}

// ---------------- fused kernel ----------------------------------------------
extern "C" __global__ __launch_bounds__(NTHR, 2)
void trans_fused(const float* __restrict__ x,
                 const float* __restrict__ L_w, const float* __restrict__ UL_w,
                 const float* __restrict__ WQ,  const float* __restrict__ WK,
                 const float* __restrict__ WVd, const float* __restrict__ WVu,
                 const float* __restrict__ WQ2, const float* __restrict__ WK2,
                 const float* __restrict__ WVd2,const float* __restrict__ WVu2,
                 const float* __restrict__ qin1,const float* __restrict__ qout1,
                 const float* __restrict__ qin2,const float* __restrict__ qout2,
                 const float* __restrict__ POSb, float* __restrict__ out)
{
    extern __shared__ float lds[];
    float* Hs = lds;                      // [80][HSTR], row = b*10 + n
    float* Qb = lds + HS_FLOATS;          // [40][QSTR], row r' = b4*10 + n ; also G / t(lo)
    float* Kb = Qb + BUF_FLOATS;          // [40][QSTR]                     ; also t(hi)
    float* Vb = Kb + BUF_FLOATS;          // [40][QSTR]
    float* Pb = Vb + BUF_FLOATS;          // [8][10][12] logits -> softmax weights
    float* Tb = Qb;                       // t buffer: 80 rows spanning Qb+Kb

    const int tid = threadIdx.x;
    const int gb0 = blockIdx.x * BT;

    // ---- Phase 0: h = x @ L_w + POS (fp64 accum) ----
    for (int idx = tid; idx < NHROWS * TD; idx += NTHR) {
        int r = idx >> 7, d = idx & 127;
        int b = r / 10, n = r - b * 10;
        const float* xp = x + ((size_t)(gb0 + b) * TS + n) * 4;
        double acc = (double)POSb[n * TD + d];
#pragma unroll
        for (int c = 0; c < 4; c++)
            acc += (double)xp[c] * (double)L_w[c * TD + d];
        Hs[r * HSTR + d] = (float)acc;
    }
    __syncthreads();

    for (int layer = 0; layer < 2; ++layer) {
        const float* pWQ  = layer ? WQ2  : WQ;
        const float* pWK  = layer ? WK2  : WK;
        const float* pWVd = layer ? WVd2 : WVd;
        const float* pWVu = layer ? WVu2 : WVu;
        const float* pqin = layer ? qin2 : qin1;
        const float* pqou = layer ? qout2 : qout1;

        for (int hb = 0; hb < 2; ++hb) {
            // ---- QKV (fp32): 240 tiles = mat(3) x n(10) x cg(8); m over b4 ----
            if (tid < 240) {
                int p = tid / 80, t2 = tid % 80;
                int n = t2 >> 3, cg = t2 & 7;
                const float* Wp = (p == 0 ? pWQ : (p == 1 ? pWK : pWVd)) + cg * 8;
                float* Ob = (p == 0 ? Qb : (p == 1 ? Kb : Vb));
                gemm_f32<4, 8, TD, false>(Hs, (hb * 40 + n) * HSTR, 10 * HSTR,
                                          Wp, TE,
                                          Ob, n * QSTR + cg * 8, 10 * QSTR, 1.f);
            }
            __syncthreads();

            // ---- logits (fp64 dot): 220 = b4(4) x 55 (i,j<=i) ----
            if (tid < 220) {
                int b4 = tid / 55, pr = tid % 55;
                int i = 0, base = 0;
                while (pr >= base + i + 1) { base += i + 1; i++; }
                int j = pr - base;
                const float* qr = Qb + (b4 * 10 + i) * QSTR;
                const float* kr = Kb + (b4 * 10 + j) * QSTR;
                double acc = 0.0;
                for (int e = 0; e < TE; e += 4) {
                    float4 q4 = *(const float4*)(qr + e);
                    float4 k4 = *(const float4*)(kr + e);
                    acc = fma((double)q4.x, (double)k4.x, acc);
                    acc = fma((double)q4.y, (double)k4.y, acc);
                    acc = fma((double)q4.z, (double)k4.z, acc);
                    acc = fma((double)q4.w, (double)k4.w, acc);
                }
                Pb[(hb * 4 + b4) * 120 + i * 12 + j] = (float)acc;
            }
            __syncthreads();

            // ---- softmax over keys j<=i (fp32, matches reference) ----
            if (tid < 40) {
                int b4 = tid / 10, i = tid % 10;
                float* pr = Pb + (hb * 4 + b4) * 120 + i * 12;
                float m = pr[0];
#pragma unroll
                for (int j = 1; j < TS; j++) if (j <= i) m = fmaxf(m, pr[j]);
                float sum = 0.f;
#pragma unroll
                for (int j = 0; j < TS; j++) if (j <= i) { float e = expf(pr[j] - m); pr[j] = e; sum += e; }
#pragma unroll
                for (int j = 0; j < TS; j++) pr[j] = (j <= i) ? pr[j] / sum : 0.f;
            }
            __syncthreads();

            // ---- G[r'=b4*10+q][e] = sum_k P * Vd[b4*10+k][e]; into Qb (Q dead) ----
            for (int oi = tid; oi < 40 * 16; oi += NTHR) {
                int rr = oi >> 4, e4 = (oi & 15) * 4;
                int b4 = rr / 10, q = rr - b4 * 10;
                const float* pp = Pb + (hb * 4 + b4) * 120 + q * 12;
                float4 g = {0.f, 0.f, 0.f, 0.f};
#pragma unroll
                for (int k = 0; k < TS; k++) {
                    float p = pp[k];
                    float4 v = *(const float4*)(Vb + (b4 * 10 + k) * QSTR + e4);
                    g.x = fmaf(p, v.x, g.x);
                    g.y = fmaf(p, v.y, g.y);
                    g.z = fmaf(p, v.z, g.z);
                    g.w = fmaf(p, v.w, g.w);
                }
                *(float4*)(Qb + rr * QSTR + e4) = g;
            }
            __syncthreads();

            // ---- DE: Hs(half) += invsqrt10 * G @ WVu ; 160 tiles = q(10) x cg(16) ----
            if (tid < 160) {
                int q = tid >> 4, cg = tid & 15;
                gemm_f32<4, 8, TE, true>(Qb, q * QSTR, 10 * QSTR,
                                         pWVu + cg * 8, TD,
                                         Hs, (hb * 40 + q) * HSTR + cg * 8, 10 * HSTR,
                                         INVSQRT10);
            }
            __syncthreads();
        } // hb

        // ---- ques-in: t[80][64] = Hs @ quesin[n] ; 160 tiles = bg(2) x n(10) x cg(8) ----
        if (tid < 160) {
            int bg = tid / 80, t2 = tid % 80;
            int n = t2 >> 3, cg = t2 & 7;
            gemm_f32<4, 8, TD, false>(Hs, (bg * 40 + n) * HSTR, 10 * HSTR,
                                      pqin + (size_t)n * TD * TE + cg * 8, TE,
                                      Tb, (bg * 40 + n) * QSTR + cg * 8, 10 * QSTR, 1.f);
        }
        __syncthreads();

        // ---- ques-out: Hs = t @ quesout[n] ; 320 tiles = bg(2) x n(10) x cg(16) ----
        for (int tile = tid; tile < 320; tile += NTHR) {
            int bg = tile / 160, t2 = tile % 160;
            int n = t2 >> 4, cg = t2 & 15;
            gemm_f32<4, 8, TE, false>(Tb, (bg * 40 + n) * QSTR, 10 * QSTR,
                                      pqou + (size_t)n * TE * TD + cg * 8, TD,
                                      Hs, (bg * 40 + n) * HSTR + cg * 8, 10 * HSTR, 1.f);
        }
        __syncthreads();
    } // layer

    // ---- out = Hs @ UL_w : 320 outs, grid-stride ----
    for (int idx = tid; idx < NHROWS * 4; idx += NTHR) {
        int r = idx >> 2, c = idx & 3;
        int b = r / 10, n = r - b * 10;
        const float* hr = Hs + r * HSTR;
        float acc = 0.f;
        for (int d = 0; d < TD; d += 4) {
            float4 h4 = *(const float4*)(hr + d);
            acc = fmaf(h4.x, UL_w[(d + 0) * 4 + c], acc);
            acc = fmaf(h4.y, UL_w[(d + 1) * 4 + c], acc);
            acc = fmaf(h4.z, UL_w[(d + 2) * 4 + c], acc);
            acc = fmaf(h4.w, UL_w[(d + 3) * 4 + c], acc);
        }
        out[((size_t)(gb0 + b) * TS + n) * 4 + c] = acc;
    }
}

// ---------------- host launch -----------------------------------------------
extern "C" void kernel_launch(void* const* d_in, const int* in_sizes, int n_in,
                              void* d_out, int out_size, void* d_ws, size_t ws_size,
                              hipStream_t stream) {
    const float* x    = (const float*)d_in[0];
    const float* L_w  = (const float*)d_in[1];
    const float* UL_w = (const float*)d_in[2];
    const float* WQ   = (const float*)d_in[3];
    const float* WK   = (const float*)d_in[4];
    const float* WVd  = (const float*)d_in[5];
    const float* WVu  = (const float*)d_in[6];
    const float* WQ2  = (const float*)d_in[7];
    const float* WK2  = (const float*)d_in[8];
    const float* WVd2 = (const float*)d_in[9];
    const float* WVu2 = (const float*)d_in[10];
    const float* qin1 = (const float*)d_in[11];
    const float* qout1= (const float*)d_in[12];
    const float* qin2 = (const float*)d_in[13];
    const float* qout2= (const float*)d_in[14];
    float* out = (float*)d_out;
    float* POSb = (float*)d_ws;

    int B = in_sizes[0] / (TS * 4);
    size_t lds_bytes = (size_t)LDS_FLOATS * sizeof(float);

    (void)hipFuncSetAttribute((const void*)trans_fused,
                              hipFuncAttributeMaxDynamicSharedMemorySize,
                              (int)lds_bytes);

    pos_kernel<<<dim3(1), dim3(256), 0, stream>>>(POSb);
    trans_fused<<<dim3(B / BT), dim3(NTHR), lds_bytes, stream>>>(
        x, L_w, UL_w, WQ, WK, WVd, WVu, WQ2, WK2, WVd2, WVu2,
        qin1, qout1, qin2, qout2, POSb, out);
}

// Round 4
// 1251.624 us; speedup vs baseline: 1.2123x; 1.0221x over previous
//
#include <hip/hip_runtime.h>
#include <math.h>

#define TS 10
#define TD 128
#define TE 64
#define BT 8
#define NTHR 256
#define HSTR 132          // floats per Hs row: 128+4 pad (row step = 4 banks mod 32)
#define QSTR 68           // floats per Q/K/Vd/G/t row: 64+4 pad
#define NHROWS (TS*BT)    // 80

#define HS_FLOATS (NHROWS*HSTR)    // 10560
#define BUF_FLOATS (40*QSTR)       // 2720
#define P_FLOATS (BT*TS*12)        // 960
#define LDS_FLOATS (HS_FLOATS + 3*BUF_FLOATS + P_FLOATS)   // 19680 -> 78720 B (2 WG/CU)

#define INVSQRT10 0.31622776601683794f

// ---------------- POS precompute (fp64, once per launch, into d_ws) ----------
__global__ void pos_kernel(float* __restrict__ pos) {
    for (int idx = threadIdx.x; idx < TS * TD; idx += blockDim.x) {
        int n = idx / TD, d = idx % TD;
        int j = d >> 1;
        double ang = (double)n / pow(1000.0, 2.0 * (double)j / (double)TD);
        double v = (d & 1) ? cos(ang) : sin(ang);
        pos[idx] = (float)v;
    }
}

// ---------------- M-row x C-col fp32 GEMM tile, register double-buffered -----
// OUT[m][c] = sum_k A[a0+m*astr+k] * W[k*ws+c].  A,O in LDS; W in global.
// K multiple of 8. Global W prefetch issues first (longest latency), then LDS A;
// both for step k+4 issue BEFORE the FMA block of step k.
template <int M, int C, int K, bool ADD>
__device__ __forceinline__ void gemm_f32(
    const float* __restrict__ Ap, int a0, int astr,
    const float* __restrict__ W, int ws,
    float* __restrict__ Op, int o0, int ostr,
    float scale)
{
    constexpr int CG = C / 4;
    float acc[M][C];
#pragma unroll
    for (int m = 0; m < M; m++)
#pragma unroll
        for (int c = 0; c < C; c++) acc[m][c] = 0.f;

    float4 aR0[M], aR1[M], wR0[4 * CG], wR1[4 * CG];

    auto loadW = [&](float4* wR, int k) {
#pragma unroll
        for (int kk = 0; kk < 4; kk++)
#pragma unroll
            for (int cg = 0; cg < CG; cg++)
                wR[kk * CG + cg] = *(const float4*)(W + (size_t)(k + kk) * ws + cg * 4);
    };
    auto loadA = [&](float4* aR, int k) {
#pragma unroll
        for (int m = 0; m < M; m++)
            aR[m] = *(const float4*)(Ap + a0 + m * astr + k);
    };
    auto compute = [&](const float4* aR, const float4* wR) {
#pragma unroll
        for (int m = 0; m < M; m++) {
            const float* af = (const float*)&aR[m];
#pragma unroll
            for (int kk = 0; kk < 4; kk++) {
                float a = af[kk];
#pragma unroll
                for (int cg = 0; cg < CG; cg++) {
                    const float* wf = (const float*)&wR[kk * CG + cg];
#pragma unroll
                    for (int j = 0; j < 4; j++)
                        acc[m][cg * 4 + j] = fmaf(a, wf[j], acc[m][cg * 4 + j]);
                }
            }
        }
    };

    loadW(wR0, 0); loadA(aR0, 0);
    int k = 0;
#pragma unroll 1
    for (; k + 8 < K; k += 8) {
        loadW(wR1, k + 4); loadA(aR1, k + 4);   // prefetch k+4
        compute(aR0, wR0);                      // compute k
        loadW(wR0, k + 8); loadA(aR0, k + 8);   // prefetch k+8
        compute(aR1, wR1);                      // compute k+4
    }
    loadW(wR1, K - 4); loadA(aR1, K - 4);
    compute(aR0, wR0);
    compute(aR1, wR1);

#pragma unroll
    for (int m = 0; m < M; m++) {
        float* op = Op + o0 + m * ostr;
#pragma unroll
        for (int cg = 0; cg < CG; cg++) {
            float4 r;
            if constexpr (ADD) {
                float4 v = *(float4*)(op + cg * 4);
                r.x = fmaf(scale, acc[m][cg * 4 + 0], v.x);
                r.y = fmaf(scale, acc[m][cg * 4 + 1], v.y);
                r.z = fmaf(scale, acc[m][cg * 4 + 2], v.z);
                r.w = fmaf(scale, acc[m][cg * 4 + 3], v.w);
            } else {
                r.x = scale * acc[m][cg * 4 + 0];
                r.y = scale * acc[m][cg * 4 + 1];
                r.z = scale * acc[m][cg * 4 + 2];
                r.w = scale * acc[m][cg * 4 + 3];
            }
            *(float4*)(op + cg * 4) = r;
        }
    }
}

// ---------------- fused kernel ----------------------------------------------
extern "C" __global__ __launch_bounds__(NTHR, 2)
void trans_fused(const float* __restrict__ x,
                 const float* __restrict__ L_w, const float* __restrict__ UL_w,
                 const float* __restrict__ WQ,  const float* __restrict__ WK,
                 const float* __restrict__ WVd, const float* __restrict__ WVu,
                 const float* __restrict__ WQ2, const float* __restrict__ WK2,
                 const float* __restrict__ WVd2,const float* __restrict__ WVu2,
                 const float* __restrict__ qin1,const float* __restrict__ qout1,
                 const float* __restrict__ qin2,const float* __restrict__ qout2,
                 const float* __restrict__ POSb, float* __restrict__ out)
{
    extern __shared__ float lds[];
    float* Hs = lds;                      // [80][HSTR], row = b*10 + n
    float* Qb = lds + HS_FLOATS;          // [40][QSTR], row r' = b4*10 + n ; also G / t(lo)
    float* Kb = Qb + BUF_FLOATS;          // [40][QSTR]                     ; also t(hi)
    float* Vb = Kb + BUF_FLOATS;          // [40][QSTR]
    float* Pb = Vb + BUF_FLOATS;          // [8][10][12] logits -> softmax weights
    float* Tb = Qb;                       // t buffer: 80 rows spanning Qb+Kb

    const int tid = threadIdx.x;
    // Rotated thread id: moves partial-phase load/idle windows across waves
    // (and thus SIMDs) per block, so co-resident WGs fill each other's gaps.
    const int vtid = (tid + ((blockIdx.x & 3) << 6)) & 255;
    const int gb0 = blockIdx.x * BT;

    // ---- Phase 0: h = x @ L_w + POS (fp64 accum; 40 elems/thread, balanced) ----
    for (int idx = tid; idx < NHROWS * TD; idx += NTHR) {
        int r = idx >> 7, d = idx & 127;
        int b = r / 10, n = r - b * 10;
        const float* xp = x + ((size_t)(gb0 + b) * TS + n) * 4;
        double acc = (double)POSb[n * TD + d];
#pragma unroll
        for (int c = 0; c < 4; c++)
            acc += (double)xp[c] * (double)L_w[c * TD + d];
        Hs[r * HSTR + d] = (float)acc;
    }
    __syncthreads();

    for (int layer = 0; layer < 2; ++layer) {
        const float* pWQ  = layer ? WQ2  : WQ;
        const float* pWK  = layer ? WK2  : WK;
        const float* pWVd = layer ? WVd2 : WVd;
        const float* pWVu = layer ? WVu2 : WVu;
        const float* pqin = layer ? qin2 : qin1;
        const float* pqou = layer ? qout2 : qout1;

        for (int hb = 0; hb < 2; ++hb) {
            // ---- QKV (fp32): 240 tasks = mat(3) x n(10) x cg(8); m over b4 ----
            if (vtid < 240) {
                int p = vtid / 80, t2 = vtid % 80;
                int n = t2 >> 3, cg = t2 & 7;
                const float* Wp = (p == 0 ? pWQ : (p == 1 ? pWK : pWVd)) + cg * 8;
                float* Ob = (p == 0 ? Qb : (p == 1 ? Kb : Vb));
                gemm_f32<4, 8, TD, false>(Hs, (hb * 40 + n) * HSTR, 10 * HSTR,
                                          Wp, TE,
                                          Ob, n * QSTR + cg * 8, 10 * QSTR, 1.f);
            }
            __syncthreads();

            // ---- logits (fp64, 2 chains): 220 = b4(4) x 55 (i,j<=i) ----
            if (vtid < 220) {
                int b4 = vtid / 55, pr = vtid % 55;
                int i = 0, base = 0;
                while (pr >= base + i + 1) { base += i + 1; i++; }
                int j = pr - base;
                const float* qr = Qb + (b4 * 10 + i) * QSTR;
                const float* kr = Kb + (b4 * 10 + j) * QSTR;
                double acc0 = 0.0, acc1 = 0.0;
                for (int e = 0; e < TE; e += 8) {
                    float4 qa = *(const float4*)(qr + e);
                    float4 ka = *(const float4*)(kr + e);
                    float4 qb4 = *(const float4*)(qr + e + 4);
                    float4 kb4 = *(const float4*)(kr + e + 4);
                    acc0 = fma((double)qa.x, (double)ka.x, acc0);
                    acc1 = fma((double)qb4.x, (double)kb4.x, acc1);
                    acc0 = fma((double)qa.y, (double)ka.y, acc0);
                    acc1 = fma((double)qb4.y, (double)kb4.y, acc1);
                    acc0 = fma((double)qa.z, (double)ka.z, acc0);
                    acc1 = fma((double)qb4.z, (double)kb4.z, acc1);
                    acc0 = fma((double)qa.w, (double)ka.w, acc0);
                    acc1 = fma((double)qb4.w, (double)kb4.w, acc1);
                }
                Pb[(hb * 4 + b4) * 120 + i * 12 + j] = (float)(acc0 + acc1);
            }
            __syncthreads();

            // ---- softmax over keys j<=i (fp32, matches reference) ----
            if (vtid < 40) {
                int b4 = vtid / 10, i = vtid % 10;
                float* pr = Pb + (hb * 4 + b4) * 120 + i * 12;
                float m = pr[0];
#pragma unroll
                for (int j = 1; j < TS; j++) if (j <= i) m = fmaxf(m, pr[j]);
                float sum = 0.f;
#pragma unroll
                for (int j = 0; j < TS; j++) if (j <= i) { float e = expf(pr[j] - m); pr[j] = e; sum += e; }
#pragma unroll
                for (int j = 0; j < TS; j++) pr[j] = (j <= i) ? pr[j] / sum : 0.f;
            }
            __syncthreads();

            // ---- G[r'=b4*10+q][e] = sum_k P * Vd[b4*10+k][e]; into Qb (Q dead) ----
            for (int oi = vtid; oi < 40 * 16; oi += NTHR) {
                int rr = oi >> 4, e4 = (oi & 15) * 4;
                int b4 = rr / 10;
                int q = rr - b4 * 10;
                const float* pp = Pb + (hb * 4 + b4) * 120 + q * 12;
                float4 g = {0.f, 0.f, 0.f, 0.f};
#pragma unroll
                for (int k = 0; k < TS; k++) {
                    float p = pp[k];
                    float4 v = *(const float4*)(Vb + (b4 * 10 + k) * QSTR + e4);
                    g.x = fmaf(p, v.x, g.x);
                    g.y = fmaf(p, v.y, g.y);
                    g.z = fmaf(p, v.z, g.z);
                    g.w = fmaf(p, v.w, g.w);
                }
                *(float4*)(Qb + rr * QSTR + e4) = g;
            }
            __syncthreads();

            // ---- DE: Hs(half) += invsqrt10 * G @ WVu ----
            // 256 tasks exactly: rg(8, 5 contiguous G rows) x cg(32, C=4). Balanced.
            // G row r' maps to Hs row hb*40 + r' (contiguous).
            {
                int rg = tid >> 5, cg = tid & 31;
                gemm_f32<5, 4, TE, true>(Qb, (rg * 5) * QSTR, QSTR,
                                         pWVu + cg * 4, TD,
                                         Hs, (hb * 40 + rg * 5) * HSTR + cg * 4, HSTR,
                                         INVSQRT10);
            }
            __syncthreads();
        } // hb

        // ---- ques-in: t[80][64] = Hs @ quesin[n] ; 320 tasks = n(10) x bg(2) x cg(16) ----
        for (int task = vtid; task < 320; task += NTHR) {
            int cg = task & 15, bg = (task >> 4) & 1, n = task >> 5;
            gemm_f32<4, 4, TD, false>(Hs, (bg * 40 + n) * HSTR, 10 * HSTR,
                                      pqin + (size_t)n * TD * TE + cg * 4, TE,
                                      Tb, (bg * 40 + n) * QSTR + cg * 4, 10 * QSTR, 1.f);
        }
        __syncthreads();

        // ---- ques-out: Hs = t @ quesout[n] ; 320 tasks = n(10) x bg(2) x cg(16) ----
        for (int task = vtid; task < 320; task += NTHR) {
            int cg = task & 15, bg = (task >> 4) & 1, n = task >> 5;
            gemm_f32<4, 8, TE, false>(Tb, (bg * 40 + n) * QSTR, 10 * QSTR,
                                      pqou + (size_t)n * TE * TD + cg * 8, TD,
                                      Hs, (bg * 40 + n) * HSTR + cg * 8, 10 * HSTR, 1.f);
        }
        __syncthreads();
    } // layer

    // ---- out = Hs @ UL_w : 320 outs, rotated grid-stride ----
    for (int idx = vtid; idx < NHROWS * 4; idx += NTHR) {
        int r = idx >> 2, c = idx & 3;
        int b = r / 10, n = r - b * 10;
        const float* hr = Hs + r * HSTR;
        float acc = 0.f;
        for (int d = 0; d < TD; d += 4) {
            float4 h4 = *(const float4*)(hr + d);
            acc = fmaf(h4.x, UL_w[(d + 0) * 4 + c], acc);
            acc = fmaf(h4.y, UL_w[(d + 1) * 4 + c], acc);
            acc = fmaf(h4.z, UL_w[(d + 2) * 4 + c], acc);
            acc = fmaf(h4.w, UL_w[(d + 3) * 4 + c], acc);
        }
        out[((size_t)(gb0 + b) * TS + n) * 4 + c] = acc;
    }
}

// ---------------- host launch -----------------------------------------------
extern "C" void kernel_launch(void* const* d_in, const int* in_sizes, int n_in,
                              void* d_out, int out_size, void* d_ws, size_t ws_size,
                              hipStream_t stream) {
    const float* x    = (const float*)d_in[0];
    const float* L_w  = (const float*)d_in[1];
    const float* UL_w = (const float*)d_in[2];
    const float* WQ   = (const float*)d_in[3];
    const float* WK   = (const float*)d_in[4];
    const float* WVd  = (const float*)d_in[5];
    const float* WVu  = (const float*)d_in[6];
    const float* WQ2  = (const float*)d_in[7];
    const float* WK2  = (const float*)d_in[8];
    const float* WVd2 = (const float*)d_in[9];
    const float* WVu2 = (const float*)d_in[10];
    const float* qin1 = (const float*)d_in[11];
    const float* qout1= (const float*)d_in[12];
    const float* qin2 = (const float*)d_in[13];
    const float* qout2= (const float*)d_in[14];
    float* out = (float*)d_out;
    float* POSb = (float*)d_ws;

    int B = in_sizes[0] / (TS * 4);
    size_t lds_bytes = (size_t)LDS_FLOATS * sizeof(float);

    (void)hipFuncSetAttribute((const void*)trans_fused,
                              hipFuncAttributeMaxDynamicSharedMemorySize,
                              (int)lds_bytes);

    pos_kernel<<<dim3(1), dim3(256), 0, stream>>>(POSb);
    trans_fused<<<dim3(B / BT), dim3(NTHR), lds_bytes, stream>>>(
        x, L_w, UL_w, WQ, WK, WVd, WVu, WQ2, WK2, WVd2, WVu2,
        qin1, qout1, qin2, qout2, POSb, out);
}